// Round 8
// baseline (2918.767 us; speedup 1.0000x reference)
//
#include <hip/hip_runtime.h>
#include <stdint.h>
#include <math.h>

typedef unsigned short u16;
typedef unsigned int u32;

#define EPSF 1e-8f
#define SMOOTHF 9.0f
#define SLOPEF 0.1f

__device__ __forceinline__ u16 f2bf(float f) {
  union { float f; u32 u; } v; v.f = f;
  u32 u = v.u;
  u32 r = (u + 0x7FFFu + ((u >> 16) & 1u)) >> 16;   // RNE
  return (u16)r;
}
__device__ __forceinline__ float bf2f(u16 h) {
  union { u32 u; float f; } v; v.u = ((u32)h) << 16;
  return v.f;
}

__device__ __forceinline__ float wave_red_sum(float x) {
#pragma unroll
  for (int off = 32; off; off >>= 1) x += __shfl_xor(x, off, 64);
  return x;
}

__device__ __forceinline__ float block_red_sum(float x) {
  __shared__ float rs[4];
  x = wave_red_sum(x);
  const int lane = threadIdx.x & 63, wv = threadIdx.x >> 6;
  if (lane == 0) rs[wv] = x;
  __syncthreads();
  float r = rs[0] + rs[1] + rs[2] + rs[3];
  __syncthreads();
  return r;
}

// ---------------------------------------------------------------- small prep
__global__ __launch_bounds__(256) void rownorm_kernel(
    const float* __restrict__ cap, const float* __restrict__ img,
    float* __restrict__ capn, float* __restrict__ imgn) {
  const int row = blockIdx.x;  // 0..1279 cap rows, 1280..2431 img rows
  const float* p; float* o;
  if (row < 1280) { p = cap + (size_t)row * 1024; o = capn + row; }
  else            { p = img + (size_t)(row - 1280) * 1024; o = imgn + (row - 1280); }
  float ss = 0.f;
  for (int d = threadIdx.x; d < 1024; d += 256) { float v = p[d]; ss += v * v; }
  float t = block_red_sum(ss);
  if (threadIdx.x == 0) *o = sqrtf(t);
}

__global__ __launch_bounds__(256) void dup_kernel(
    const float* __restrict__ cap, int* __restrict__ dup) {
  const int b = blockIdx.x;
  const int c = b >> 5, i = b & 31;
  float ss = 0.f;
  if (c != i) {
    const float* A = cap + (size_t)c * 40960;
    const float* B = cap + (size_t)i * 40960;
    for (int e = threadIdx.x; e < 40960; e += 256) { float d = A[e] - B[e]; ss += d * d; }
  }
  float t = block_red_sum(ss);
  if (threadIdx.x == 0) dup[b] = (c != i && t <= 1e-6f) ? 1 : 0;
}

// Wcat row n: even n -> Wl[n/2], odd n -> Wg[n/2]
__global__ __launch_bounds__(256) void wconv_kernel(
    const float* __restrict__ Wl, const float* __restrict__ Wg, u16* __restrict__ out) {
  const size_t idx = ((size_t)blockIdx.x * 256 + threadIdx.x) * 4;
  const int n = (int)(idx >> 11);
  const int k = (int)(idx & 2047);
  const float* src = (n & 1) ? &Wg[(size_t)(n >> 1) * 2048 + k] : &Wl[(size_t)(n >> 1) * 2048 + k];
  float4 v = *(const float4*)src;
  ushort4 o;
  o.x = f2bf(v.x); o.y = f2bf(v.y); o.z = f2bf(v.z); o.w = f2bf(v.w);
  *(ushort4*)&out[idx] = o;
}

// fp32 rows -> bf16, grouped in 48-row padded blocks (pad rows zeroed).
__global__ __launch_bounds__(256) void bfpad_kernel(
    const float* __restrict__ src, u16* __restrict__ dst, int nrows) {
  const int b = blockIdx.x;
  const int blk = b / 48, r = b - blk * 48;
  u16* orow = dst + (size_t)b * 1024;
  const int tid = threadIdx.x;
  ushort4 o = {0, 0, 0, 0};
  if (r < nrows) {
    const float4 v = *(const float4*)&src[((size_t)blk * nrows + r) * 1024 + tid * 4];
    o.x = f2bf(v.x); o.y = f2bf(v.y); o.z = f2bf(v.z); o.w = f2bf(v.w);
  }
  *(ushort4*)&orow[tid * 4] = o;
}

// SS[b][s][s'] = src_b[s] . src_b[s'], fp32; zero outside nrows. grid (48, 32)
__global__ __launch_bounds__(256) void ss_kernel(
    const float* __restrict__ src, float* __restrict__ out, int nrows) {
  const int s = blockIdx.x, b = blockIdx.y;
  float* orow = out + ((size_t)b * 48 + s) * 64;
  __shared__ float Ls[1024];
  const int tid = threadIdx.x;
  if (s < nrows)
    *(float4*)&Ls[tid * 4] = *(const float4*)&src[((size_t)b * nrows + s) * 1024 + tid * 4];
  __syncthreads();
  const int s2 = tid >> 2, koff = (tid & 3) * 256;
  float acc = 0.f;
  if (s < nrows && s2 < nrows) {
    const float* r2 = src + ((size_t)b * nrows + s2) * 1024 + koff;
    for (int k = 0; k < 256; k += 4) {
      float4 a = *(const float4*)&Ls[koff + k];
      float4 bb = *(const float4*)&r2[k];
      acc += a.x * bb.x + a.y * bb.y + a.z * bb.z + a.w * bb.w;
    }
  }
  acc += __shfl_xor(acc, 1, 64);
  acc += __shfl_xor(acc, 2, 64);
  if ((tid & 3) == 0) orow[s2] = acc;
}

// ---------------------------------------------------------------- GEMMs
typedef short bf16x8 __attribute__((ext_vector_type(8)));
typedef float f32x4 __attribute__((ext_vector_type(4)));

// C[m][n] = sum_{k<1024} A[m*1024+k] * B[n*2048+koff+k], out bf16.
// trans=0: out[m*2048+n].  trans=1 (SWT): m=(blk*48+s) -> out[(blk*2048+n)*64+s].
__global__ __launch_bounds__(256) void gemm_flex_kernel(
    const u16* __restrict__ A, const u16* __restrict__ B, u16* __restrict__ Cout,
    int koff, int trans) {
  __shared__ u16 As[128 * 32];
  __shared__ u16 Bs[128 * 32];
  const int tid = threadIdx.x;
  const int lane = tid & 63;
  const int wave = tid >> 6;
  const int wm = (wave >> 1) * 64;
  const int wn = (wave & 1) * 64;
  const int bm = blockIdx.x * 128;
  const int bn = blockIdx.y * 128;
  const int lr = lane & 15;
  const int lq = lane >> 4;
  f32x4 acc[4][4] = {};
  const int e0 = tid * 8;
  const int r0 = e0 >> 5;
  const int c0 = e0 & 31;
  const u16* Ag0 = A + (size_t)(bm + r0) * 1024 + c0;
  const u16* Ag1 = A + (size_t)(bm + r0 + 64) * 1024 + c0;
  const u16* Bg0 = B + (size_t)(bn + r0) * 2048 + koff + c0;
  const u16* Bg1 = B + (size_t)(bn + r0 + 64) * 2048 + koff + c0;
  u16* As0 = As + e0; u16* As1 = As + e0 + 2048;
  u16* Bs0 = Bs + e0; u16* Bs1 = Bs + e0 + 2048;
  for (int k0 = 0; k0 < 1024; k0 += 32) {
    __builtin_amdgcn_global_load_lds((const __attribute__((address_space(1))) void*)(Ag0 + k0),
                                     (__attribute__((address_space(3))) void*)As0, 16, 0, 0);
    __builtin_amdgcn_global_load_lds((const __attribute__((address_space(1))) void*)(Ag1 + k0),
                                     (__attribute__((address_space(3))) void*)As1, 16, 0, 0);
    __builtin_amdgcn_global_load_lds((const __attribute__((address_space(1))) void*)(Bg0 + k0),
                                     (__attribute__((address_space(3))) void*)Bs0, 16, 0, 0);
    __builtin_amdgcn_global_load_lds((const __attribute__((address_space(1))) void*)(Bg1 + k0),
                                     (__attribute__((address_space(3))) void*)Bs1, 16, 0, 0);
    __syncthreads();
    bf16x8 af[4], bfr[4];
#pragma unroll
    for (int mi = 0; mi < 4; mi++)
      af[mi] = *(const bf16x8*)&As[(wm + mi * 16 + lr) * 32 + lq * 8];
#pragma unroll
    for (int ni = 0; ni < 4; ni++)
      bfr[ni] = *(const bf16x8*)&Bs[(wn + ni * 16 + lr) * 32 + lq * 8];
#pragma unroll
    for (int mi = 0; mi < 4; mi++)
#pragma unroll
      for (int ni = 0; ni < 4; ni++)
        acc[mi][ni] = __builtin_amdgcn_mfma_f32_16x16x32_bf16(af[mi], bfr[ni], acc[mi][ni], 0, 0, 0);
    __syncthreads();
  }
#pragma unroll
  for (int mi = 0; mi < 4; mi++) {
#pragma unroll
    for (int ni = 0; ni < 4; ni++) {
      const int col = bn + wn + ni * 16 + lr;
      const int rowb = bm + wm + mi * 16 + lq * 4;
      if (!trans) {
#pragma unroll
        for (int r = 0; r < 4; r++)
          Cout[(size_t)(rowb + r) * 2048 + col] = f2bf(acc[mi][ni][r]);
      } else {
#pragma unroll
        for (int r = 0; r < 4; r++) {
          const int m = rowb + r;
          const int blk = m / 48, s = m - blk * 48;
          Cout[((size_t)blk * 2048 + col) * 64 + s] = f2bf(acc[mi][ni][r]);
        }
      }
    }
  }
}

// E[m][n] = sum_k imgbf[m][k]*capbf[n][k], fp32 out, M=N=1536, K=1024. grid (12,12)
__global__ __launch_bounds__(256) void gemm_e_kernel(
    const u16* __restrict__ A, const u16* __restrict__ B, float* __restrict__ C) {
  __shared__ u16 As[128 * 32];
  __shared__ u16 Bs[128 * 32];
  const int tid = threadIdx.x;
  const int lane = tid & 63;
  const int wave = tid >> 6;
  const int wm = (wave >> 1) * 64;
  const int wn = (wave & 1) * 64;
  const int bm = blockIdx.x * 128;
  const int bn = blockIdx.y * 128;
  const int lr = lane & 15;
  const int lq = lane >> 4;
  f32x4 acc[4][4] = {};
  const int e0 = tid * 8;
  const int r0 = e0 >> 5;
  const int c0 = e0 & 31;
  const u16* Ag0 = A + (size_t)(bm + r0) * 1024 + c0;
  const u16* Ag1 = A + (size_t)(bm + r0 + 64) * 1024 + c0;
  const u16* Bg0 = B + (size_t)(bn + r0) * 1024 + c0;
  const u16* Bg1 = B + (size_t)(bn + r0 + 64) * 1024 + c0;
  u16* As0 = As + e0; u16* As1 = As + e0 + 2048;
  u16* Bs0 = Bs + e0; u16* Bs1 = Bs + e0 + 2048;
  for (int k0 = 0; k0 < 1024; k0 += 32) {
    __builtin_amdgcn_global_load_lds((const __attribute__((address_space(1))) void*)(Ag0 + k0),
                                     (__attribute__((address_space(3))) void*)As0, 16, 0, 0);
    __builtin_amdgcn_global_load_lds((const __attribute__((address_space(1))) void*)(Ag1 + k0),
                                     (__attribute__((address_space(3))) void*)As1, 16, 0, 0);
    __builtin_amdgcn_global_load_lds((const __attribute__((address_space(1))) void*)(Bg0 + k0),
                                     (__attribute__((address_space(3))) void*)Bs0, 16, 0, 0);
    __builtin_amdgcn_global_load_lds((const __attribute__((address_space(1))) void*)(Bg1 + k0),
                                     (__attribute__((address_space(3))) void*)Bs1, 16, 0, 0);
    __syncthreads();
    bf16x8 af[4], bfr[4];
#pragma unroll
    for (int mi = 0; mi < 4; mi++)
      af[mi] = *(const bf16x8*)&As[(wm + mi * 16 + lr) * 32 + lq * 8];
#pragma unroll
    for (int ni = 0; ni < 4; ni++)
      bfr[ni] = *(const bf16x8*)&Bs[(wn + ni * 16 + lr) * 32 + lq * 8];
#pragma unroll
    for (int mi = 0; mi < 4; mi++)
#pragma unroll
      for (int ni = 0; ni < 4; ni++)
        acc[mi][ni] = __builtin_amdgcn_mfma_f32_16x16x32_bf16(af[mi], bfr[ni], acc[mi][ni], 0, 0, 0);
    __syncthreads();
  }
#pragma unroll
  for (int mi = 0; mi < 4; mi++)
#pragma unroll
    for (int ni = 0; ni < 4; ni++) {
      const int col = bn + wn + ni * 16 + lr;
      const int rowb = bm + wm + mi * 16 + lq * 4;
#pragma unroll
      for (int r = 0; r < 4; r++)
        C[(size_t)(rowb + r) * 1536 + col] = acc[mi][ni][r];
    }
}

// ---------------------------------------------------------------- wcgate GEMM
// BM=128 x BN=256, BK=32 (proven 64B-row LDS layout). Wave grid 2x2, 64x128/wave.
// acc[m][n] = attnTg[m][0:64].SWT[sIdx][n][0:64]  (+ step1: q[m][0:1024].Wcat[n][0:1024])
// epilogue: lin/gate (even/odd n) (+ step0: QW0) + bias -> gated u -> Uout bf16 (in-place
// safe: block reads only rows [bm,bm+128) before writing them).
__global__ __launch_bounds__(256) void wcgate_kernel(
    const u16* __restrict__ attnTg, const u16* __restrict__ q2nd,
    const u16* __restrict__ qref, const u16* __restrict__ SWT,
    const u16* __restrict__ Wcat, const u16* __restrict__ qw0,
    const float* __restrict__ bl, const float* __restrict__ bg,
    u16* __restrict__ Uout, int p0, int NQ, int step, int Mt) {
  __shared__ u16 sh[128 * 132];   // staging: As 4096 + Bs 8192 u16 (24KB); epilogue tile
  u16* As = sh;
  u16* Bs = sh + 4096;
  const int tid = threadIdx.x;
  const int lane = tid & 63;
  const int wave = tid >> 6;
  const int wm = (wave >> 1) * 64;
  const int wn = (wave & 1) * 128;
  // grouped XCD swizzle over (Mt x 8) tiles; fallback to plain if Mt % 8 != 0
  const int bid = (int)blockIdx.x;
  int bmi, bni;
  if ((Mt & 7) == 0) {
    const int xcd = bid & 7;
    const int t = bid >> 3;
    const int Mxcd = Mt >> 3;
    const int gid = t >> 6;             // 8 m x 8 n = 64 blocks per full group
    const int first_m = gid << 3;
    int gs = Mxcd - first_m; if (gs > 8) gs = 8;
    const int tt = t - (gid << 6);
    bmi = xcd * Mxcd + first_m + (tt % gs);
    bni = (tt / gs) & 7;
  } else {
    bmi = bid >> 3; bni = bid & 7;
  }
  const int bm = bmi * 128;
  const int bn = bni * 256;
  const int lr = lane & 15;
  const int lq = lane >> 4;
  const int sIdx = (p0 + bm / NQ) >> 5;
  f32x4 acc[4][8] = {};
  const int e0 = tid * 8;
  const int r0 = e0 >> 5;   // 0..63
  const int c0 = e0 & 31;
  {  // region 1: K=64, A=attnTg stride 64, B=SWT stride 64
    for (int k0 = 0; k0 < 64; k0 += 32) {
#pragma unroll
      for (int s = 0; s < 2; s++)
        __builtin_amdgcn_global_load_lds(
            (const __attribute__((address_space(1))) void*)(attnTg + (size_t)(bm + r0 + s * 64) * 64 + k0 + c0),
            (__attribute__((address_space(3))) void*)(As + e0 + s * 2048), 16, 0, 0);
#pragma unroll
      for (int j = 0; j < 4; j++)
        __builtin_amdgcn_global_load_lds(
            (const __attribute__((address_space(1))) void*)(SWT + ((size_t)sIdx * 2048 + bn + r0 + j * 64) * 64 + k0 + c0),
            (__attribute__((address_space(3))) void*)(Bs + e0 + j * 2048), 16, 0, 0);
      __syncthreads();
      bf16x8 af[4], bfr[8];
#pragma unroll
      for (int mi = 0; mi < 4; mi++)
        af[mi] = *(const bf16x8*)&As[(wm + mi * 16 + lr) * 32 + lq * 8];
#pragma unroll
      for (int ni = 0; ni < 8; ni++)
        bfr[ni] = *(const bf16x8*)&Bs[(wn + ni * 16 + lr) * 32 + lq * 8];
#pragma unroll
      for (int mi = 0; mi < 4; mi++)
#pragma unroll
        for (int ni = 0; ni < 8; ni++)
          acc[mi][ni] = __builtin_amdgcn_mfma_f32_16x16x32_bf16(af[mi], bfr[ni], acc[mi][ni], 0, 0, 0);
      __syncthreads();
    }
  }
  if (step) {  // region 2: K=1024, A=q stride 1024, B=Wcat stride 2048
    for (int k0 = 0; k0 < 1024; k0 += 32) {
#pragma unroll
      for (int s = 0; s < 2; s++)
        __builtin_amdgcn_global_load_lds(
            (const __attribute__((address_space(1))) void*)(q2nd + (size_t)(bm + r0 + s * 64) * 1024 + k0 + c0),
            (__attribute__((address_space(3))) void*)(As + e0 + s * 2048), 16, 0, 0);
#pragma unroll
      for (int j = 0; j < 4; j++)
        __builtin_amdgcn_global_load_lds(
            (const __attribute__((address_space(1))) void*)(Wcat + (size_t)(bn + r0 + j * 64) * 2048 + k0 + c0),
            (__attribute__((address_space(3))) void*)(Bs + e0 + j * 2048), 16, 0, 0);
      __syncthreads();
      bf16x8 af[4], bfr[8];
#pragma unroll
      for (int mi = 0; mi < 4; mi++)
        af[mi] = *(const bf16x8*)&As[(wm + mi * 16 + lr) * 32 + lq * 8];
#pragma unroll
      for (int ni = 0; ni < 8; ni++)
        bfr[ni] = *(const bf16x8*)&Bs[(wn + ni * 16 + lr) * 32 + lq * 8];
#pragma unroll
      for (int mi = 0; mi < 4; mi++)
#pragma unroll
        for (int ni = 0; ni < 8; ni++)
          acc[mi][ni] = __builtin_amdgcn_mfma_f32_16x16x32_bf16(af[mi], bfr[ni], acc[mi][ni], 0, 0, 0);
      __syncthreads();
    }
  }
  // epilogue: C/D layout col=lane&15, row=quad*4+reg
  const bool evn = (lane & 1) == 0;
#pragma unroll
  for (int mi = 0; mi < 4; mi++) {
#pragma unroll
    for (int ni = 0; ni < 8; ni++) {
      const int ncol = bn + wn + ni * 16 + lr;
      const int d = ncol >> 1;
      const int dloc = (wn + ni * 16 + lr) >> 1;    // 0..127
      const int rowloc0 = wm + mi * 16 + lq * 4;
      const float blv = bl[d];
      const float bgv = bg[d];
#pragma unroll
      for (int r = 0; r < 4; r++) {
        const float v = acc[mi][ni][r];
        const float o = __shfl_xor(v, 1, 64);
        float lin = (evn ? v : o) + blv;
        float gt = (evn ? o : v) + bgv;
        const int m = bm + rowloc0 + r;
        const int pl = m / NQ;
        const int q = m - pl * NQ;
        float qv;
        if (step == 0) {
          const int rIdx = (p0 + pl) & 31;
          const u32 qwpair = *(const u32*)&qw0[(size_t)(rIdx * 48 + q) * 2048 + (ncol & ~1)];
          lin += bf2f((u16)(qwpair & 0xffffu));
          gt += bf2f((u16)(qwpair >> 16));
          qv = bf2f(qref[(size_t)(rIdx * 48 + q) * 1024 + d]);
        } else {
          qv = bf2f(qref[(size_t)m * 1024 + d]);
        }
        lin = fminf(fmaxf(lin, -30.f), 30.f);
        gt = fminf(fmaxf(gt, -30.f), 30.f);
        const float g = 1.f / (1.f + __expf(-gt));
        const float e2 = __expf(-2.f * lin);
        const float th = (1.f - e2) / (1.f + e2);
        const float u = qv * g + th * (1.f - g);
        if (evn) sh[(rowloc0 + r) * 132 + dloc] = f2bf(u);
      }
    }
  }
  __syncthreads();
  {  // coalesced store of 128x128 u16 tile: 2 threads per row, 128B each
    const int rowloc = tid >> 1, half = tid & 1;
    u16* dst = Uout + (size_t)(bm + rowloc) * 1024 + (bn >> 1) + half * 64;
    const u16* srcl = sh + rowloc * 132 + half * 64;
#pragma unroll
    for (int v2 = 0; v2 < 8; v2++)
      *(bf16x8*)(dst + v2 * 8) = *(const bf16x8*)(srcl + v2 * 8);
  }
}

// q_new = u / (||u|| + eps), in-place (M x 1024 bf16). One wave per row.
__global__ __launch_bounds__(256) void qnorm_kernel(u16* __restrict__ Q) {
  const int m = blockIdx.x * 4 + (threadIdx.x >> 6);
  const int lane = threadIdx.x & 63;
  u16* p = Q + (size_t)m * 1024;
  float v[16];
  float ss = 0.f;
#pragma unroll
  for (int t = 0; t < 4; t++) {
    ushort4 uv = *(const ushort4*)&p[t * 256 + lane * 4];
    float a = bf2f(uv.x), b = bf2f(uv.y), c = bf2f(uv.z), dd = bf2f(uv.w);
    v[t * 4 + 0] = a; v[t * 4 + 1] = b; v[t * 4 + 2] = c; v[t * 4 + 3] = dd;
    ss += a * a + b * b + c * c + dd * dd;
  }
  ss = wave_red_sum(ss);
  const float inv = 1.f / (sqrtf(ss) + EPSF);
#pragma unroll
  for (int t = 0; t < 4; t++) {
    ushort4 ov;
    ov.x = f2bf(v[t * 4 + 0] * inv); ov.y = f2bf(v[t * 4 + 1] * inv);
    ov.z = f2bf(v[t * 4 + 2] * inv); ov.w = f2bf(v[t * 4 + 3] * inv);
    *(ushort4*)&p[t * 256 + lane * 4] = ov;
  }
}

// ---------------------------------------------------------------- fused attention step
// A (steps 1,2): QK^T MFMA; step0: logits = E block. B: leaky/l2norm/softmax (fp32).
// C': num = a.E-col, pss = a^T SS a (LDS algebra). Writes attnT (steps 0,1).
template <int NS, int NQ>
__global__ __launch_bounds__(256) void attn_step_kernel(
    const u16* __restrict__ Sbf, const float* __restrict__ E,
    const float* __restrict__ SS, const float* __restrict__ refn,
    const u16* __restrict__ qsrc, u16* __restrict__ attnTg,
    const int* __restrict__ dup, float* __restrict__ total,
    int p0, int t2i, int step) {
  constexpr int NQW = NQ / 4;
  const int pl = blockIdx.x;
  const int plg = p0 + pl;                 // pairs sIdx-grouped
  const int sIdx = plg >> 5, rIdx = plg & 31;
  const int c = t2i ? rIdx : sIdx;
  const int i = t2i ? sIdx : rIdx;
  const int gp = c * 32 + i;
  const u16* Sb = Sbf + (size_t)sIdx * 48 * 1024;
  const float* rn = refn + (size_t)rIdx * NQ;
  const u16* Qb = qsrc + (size_t)pl * NQ * 1024;

  __shared__ float redbuf[9600];   // phase A red[4][2400]; later Elw[48*65] + SSl[48*65]
  __shared__ float attnS[2304];
  __shared__ float redcos[48];
  float* Elw = redbuf;
  float* SSl = redbuf + 3120;

  const int tid = threadIdx.x;
  const int lane = tid & 63, wave = tid >> 6;
  const int lr = lane & 15, quad = lane >> 4;

  if (step == 0) {
    for (int e = tid; e < 2304; e += 256) {
      int s, q; float v;
      if (t2i) { s = e / 48; q = e - s * 48; v = E[(size_t)(i * 48 + s) * 1536 + c * 48 + q]; }
      else     { q = e / 48; s = e - q * 48; v = E[(size_t)(i * 48 + q) * 1536 + c * 48 + s]; }
      attnS[s * 48 + q] = v;
    }
  } else {
    // phase A: wave w covers k in [w*256, w*256+256); 8 slabs x 3x3 MFMA frags
    f32x4 acc[3][3] = {};
    const int kw = wave * 256;
    const u16* Arow[3]; const u16* Brow[3];
#pragma unroll
    for (int a = 0; a < 3; a++) {
      Arow[a] = Sb + (size_t)(a * 16 + lr) * 1024 + quad * 8;
      Brow[a] = Qb + (size_t)(a * 16 + lr) * 1024 + quad * 8;
    }
    bf16x8 A0[3], B0[3], A1[3], B1[3];
#pragma unroll
    for (int a = 0; a < 3; a++) {
      A0[a] = *(const bf16x8*)(Arow[a] + kw);
      B0[a] = *(const bf16x8*)(Brow[a] + kw);
    }
#pragma unroll
    for (int j = 0; j < 8; j++) {
      if (j < 7) {
        const int kn = kw + (j + 1) * 32;
#pragma unroll
        for (int a = 0; a < 3; a++) {
          A1[a] = *(const bf16x8*)(Arow[a] + kn);
          B1[a] = *(const bf16x8*)(Brow[a] + kn);
        }
      }
#pragma unroll
      for (int a = 0; a < 3; a++)
#pragma unroll
        for (int b = 0; b < 3; b++)
          acc[a][b] = __builtin_amdgcn_mfma_f32_16x16x32_bf16(A0[a], B0[b], acc[a][b], 0, 0, 0);
#pragma unroll
      for (int a = 0; a < 3; a++) { A0[a] = A1[a]; B0[a] = B1[a]; }
    }
    float* myred = redbuf + wave * 2400;
#pragma unroll
    for (int a = 0; a < 3; a++)
#pragma unroll
      for (int b = 0; b < 3; b++) {
        const int col = b * 16 + lr;
        const int row0 = a * 16 + quad * 4;
#pragma unroll
        for (int r = 0; r < 4; r++)
          myred[(row0 + r) * 50 + col] = acc[a][b][r];
      }
    __syncthreads();
#pragma unroll
    for (int t = 0; t < 9; t++) {
      const int e = tid + t * 256;
      const int s = e / 48, q = e - s * 48;
      const int o = s * 50 + q;
      attnS[e] = redbuf[o] + redbuf[2400 + o] + redbuf[4800 + o] + redbuf[7200 + o];
    }
  }
  __syncthreads();
  // load Elw / SSl (into dead red space) + leaky/l2norm in one interval
  for (int e = tid; e < 2304; e += 256) {
    int s, q; float v;
    if (t2i) { s = e / 48; q = e - s * 48; v = E[(size_t)(i * 48 + s) * 1536 + c * 48 + q]; }
    else     { q = e / 48; s = e - q * 48; v = E[(size_t)(i * 48 + q) * 1536 + c * 48 + s]; }
    Elw[s * 65 + q] = v;
  }
  for (int e = tid; e < 48 * 64; e += 256) {
    const int s = e >> 6, s2 = e & 63;
    SSl[s * 65 + s2] = SS[((size_t)sIdx * 48 + s) * 64 + s2];
  }
  if (tid < NS) {
    float row[NQ];
    float ss = 0.f;
#pragma unroll
    for (int q = 0; q < NQ; q++) {
      float v = attnS[tid * 48 + q];
      v = (v > 0.f) ? v : SLOPEF * v;
      row[q] = v; ss += v * v;
    }
    const float inv = 1.f / (sqrtf(ss) + EPSF);
#pragma unroll
    for (int q = 0; q < NQ; q++) attnS[tid * 48 + q] = row[q] * inv;
  }
  __syncthreads();
  if (tid < NQ) {
    float mx = -1e30f;
#pragma unroll
    for (int s = 0; s < NS; s++) mx = fmaxf(mx, attnS[s * 48 + tid]);
    float ex[NS]; float sum = 0.f;
#pragma unroll
    for (int s = 0; s < NS; s++) {
      float t = __expf(SMOOTHF * (attnS[s * 48 + tid] - mx));
      ex[s] = t; sum += t;
    }
    const float inv = 1.f / sum;
#pragma unroll
    for (int s = 0; s < NS; s++) attnS[s * 48 + tid] = ex[s] * inv;
  }
  __syncthreads();
  // write attnT rows (steps 0,1): [m = pl*NQ+q][64 s]
  if (step < 2) {
    for (int e = tid; e < NQ * 64; e += 256) {
      const int q = e >> 6, s = e & 63;
      attnTg[((size_t)(pl * NQ + q)) * 64 + s] = (s < 48) ? f2bf(attnS[s * 48 + q]) : (u16)0;
    }
  }
  // phase C': per-q num & pss via E/SS algebra
  {
    const int qbase = wave * NQW;
#pragma unroll
    for (int qq = 0; qq < NQW; qq++) {
      const int q = qbase + qq;
      const float a_l = (lane < 48) ? attnS[lane * 48 + q] : 0.f;
      float t = 0.f;
#pragma unroll
      for (int s = 0; s < NS; s++)
        t += attnS[s * 48 + q] * SSl[s * 65 + lane];
      float pssv = wave_red_sum(a_l * t);
      float numv = wave_red_sum(a_l * Elw[lane * 65 + q]);
      if (lane == 0) redcos[q] = numv / fmaxf(rn[q] * sqrtf(pssv), EPSF);
    }
  }
  __syncthreads();
  if (tid == 0) {
    float sim = 0.f;
#pragma unroll
    for (int q = 0; q < NQ; q++) sim += redcos[q];
    sim *= (1.0f / NQ);
    atomicAdd(&total[gp], dup[gp] ? -1.0f : sim);
  }
}

// ---------------------------------------------------------------- launcher
extern "C" void kernel_launch(void* const* d_in, const int* in_sizes, int n_in,
                              void* d_out, int out_size, void* d_ws, size_t ws_size,
                              hipStream_t stream) {
  (void)in_sizes; (void)n_in;
  const float* img = (const float*)d_in[0];
  const float* cap = (const float*)d_in[1];
  const float* W_lt2i = (const float*)d_in[2];
  const float* b_lt2i = (const float*)d_in[3];
  const float* W_gt2i = (const float*)d_in[4];
  const float* b_gt2i = (const float*)d_in[5];
  const float* W_li2t = (const float*)d_in[6];
  const float* b_li2t = (const float*)d_in[7];
  const float* W_gi2t = (const float*)d_in[8];
  const float* b_gi2t = (const float*)d_in[9];
  float* total = (float*)d_out;

  char* ws = (char*)d_ws;
  size_t off = 0;
  auto alloc = [&](size_t b) { void* p = ws + off; off += (b + 255) & ~(size_t)255; return p; };
  u16* Wcat = (u16*)alloc((size_t)2048 * 2048 * 2);
  u16* imgbf = (u16*)alloc((size_t)32 * 48 * 1024 * 2);
  u16* capbf = (u16*)alloc((size_t)32 * 48 * 1024 * 2);
  float* capn = (float*)alloc(1280 * 4);
  float* imgn = (float*)alloc(1152 * 4);
  int* dupb = (int*)alloc(1024 * 4);
  u16* SWT = (u16*)alloc((size_t)32 * 2048 * 64 * 2);
  float* E = (float*)alloc((size_t)1536 * 1536 * 4);
  float* SSi = (float*)alloc((size_t)32 * 48 * 64 * 4);
  float* SSc = (float*)alloc((size_t)32 * 48 * 64 * 4);
  u16* QW0 = (u16*)alloc((size_t)1536 * 2048 * 2);
  const size_t fixed = off;

  // in-place q update (no double buffer) -> P=1024 fits comfortably
  static const int cands[6] = {1024, 512, 256, 128, 64, 32};
  int P = 32;
  for (int ci = 0; ci < 6; ci++) {
    const int cand = cands[ci];
    const size_t cA = (((size_t)cand * 40 * 1024 * 2) + 255) & ~(size_t)255;
    const size_t aT = (((size_t)cand * 40 * 64 * 2) + 255) & ~(size_t)255;
    if (fixed + cA + aT <= ws_size) { P = cand; break; }
  }
  u16* catA = (u16*)alloc((size_t)P * 40 * 1024 * 2);
  u16* attnTg = (u16*)alloc((size_t)P * 40 * 64 * 2);

  hipMemsetAsync(d_out, 0, (size_t)out_size * sizeof(float), stream);
  hipMemsetAsync(SWT, 0, (size_t)32 * 2048 * 64 * 2, stream);
  rownorm_kernel<<<dim3(2432), dim3(256), 0, stream>>>(cap, img, capn, imgn);
  dup_kernel<<<dim3(1024), dim3(256), 0, stream>>>(cap, dupb);
  bfpad_kernel<<<dim3(1536), dim3(256), 0, stream>>>(cap, capbf, 40);
  bfpad_kernel<<<dim3(1536), dim3(256), 0, stream>>>(img, imgbf, 36);
  gemm_e_kernel<<<dim3(12, 12), dim3(256), 0, stream>>>(imgbf, capbf, E);
  ss_kernel<<<dim3(48, 32), dim3(256), 0, stream>>>(img, SSi, 36);
  ss_kernel<<<dim3(48, 32), dim3(256), 0, stream>>>(cap, SSc, 40);

  const int nch = 1024 / P;
  for (int dir = 0; dir < 2; dir++) {
    const int t2i = (dir == 0) ? 1 : 0;
    const float* Wl = t2i ? W_lt2i : W_li2t;
    const float* Wg = t2i ? W_gt2i : W_gi2t;
    const float* bl = t2i ? b_lt2i : b_li2t;
    const float* bg = t2i ? b_gt2i : b_gi2t;
    const u16* Sbf = t2i ? imgbf : capbf;
    const u16* Refbf = t2i ? capbf : imgbf;
    const float* SSd = t2i ? SSi : SSc;
    const float* refn = t2i ? capn : imgn;
    const int NQ = t2i ? 40 : 36;
    const int Mrows = P * NQ;
    const int Mt = Mrows / 128;
    wconv_kernel<<<dim3(4096), dim3(256), 0, stream>>>(Wl, Wg, Wcat);
    gemm_flex_kernel<<<dim3(12, 16), dim3(256), 0, stream>>>(Sbf, Wcat, SWT, 1024, 1);
    gemm_flex_kernel<<<dim3(12, 16), dim3(256), 0, stream>>>(Refbf, Wcat, QW0, 0, 0);
    for (int ch = 0; ch < nch; ch++) {
      const int p0 = ch * P;
      for (int step = 0; step < 3; step++) {
        if (t2i)
          attn_step_kernel<36, 40><<<dim3(P), dim3(256), 0, stream>>>(
              Sbf, E, SSd, refn, catA, attnTg, dupb, total, p0, 1, step);
        else
          attn_step_kernel<40, 36><<<dim3(P), dim3(256), 0, stream>>>(
              Sbf, E, SSd, refn, catA, attnTg, dupb, total, p0, 0, step);
        if (step < 2) {
          wcgate_kernel<<<dim3(Mt * 8), dim3(256), 0, stream>>>(
              attnTg, catA, (step == 0) ? Refbf : catA, SWT, Wcat, QW0,
              bl, bg, catA, p0, NQ, step, Mt);
          qnorm_kernel<<<dim3(Mrows / 4), dim3(256), 0, stream>>>(catA);
        }
      }
    }
  }
}

// Round 9
// 2118.095 us; speedup vs baseline: 1.3780x; 1.3780x over previous
//
#include <hip/hip_runtime.h>
#include <stdint.h>
#include <math.h>

typedef unsigned short u16;
typedef unsigned int u32;

#define EPSF 1e-8f
#define SMOOTHF 9.0f
#define SLOPEF 0.1f

__device__ __forceinline__ u16 f2bf(float f) {
  union { float f; u32 u; } v; v.f = f;
  u32 u = v.u;
  u32 r = (u + 0x7FFFu + ((u >> 16) & 1u)) >> 16;   // RNE
  return (u16)r;
}
__device__ __forceinline__ float bf2f(u16 h) {
  union { u32 u; float f; } v; v.u = ((u32)h) << 16;
  return v.f;
}

__device__ __forceinline__ float wave_red_sum(float x) {
#pragma unroll
  for (int off = 32; off; off >>= 1) x += __shfl_xor(x, off, 64);
  return x;
}

__device__ __forceinline__ float block_red_sum(float x) {
  __shared__ float rs[4];
  x = wave_red_sum(x);
  const int lane = threadIdx.x & 63, wv = threadIdx.x >> 6;
  if (lane == 0) rs[wv] = x;
  __syncthreads();
  float r = rs[0] + rs[1] + rs[2] + rs[3];
  __syncthreads();
  return r;
}

// ---------------------------------------------------------------- small prep
__global__ __launch_bounds__(256) void rownorm_kernel(
    const float* __restrict__ cap, const float* __restrict__ img,
    float* __restrict__ capn, float* __restrict__ imgn) {
  const int row = blockIdx.x;  // 0..1279 cap rows, 1280..2431 img rows
  const float* p; float* o;
  if (row < 1280) { p = cap + (size_t)row * 1024; o = capn + row; }
  else            { p = img + (size_t)(row - 1280) * 1024; o = imgn + (row - 1280); }
  float ss = 0.f;
  for (int d = threadIdx.x; d < 1024; d += 256) { float v = p[d]; ss += v * v; }
  float t = block_red_sum(ss);
  if (threadIdx.x == 0) *o = sqrtf(t);
}

__global__ __launch_bounds__(256) void dup_kernel(
    const float* __restrict__ cap, int* __restrict__ dup) {
  const int b = blockIdx.x;
  const int c = b >> 5, i = b & 31;
  float ss = 0.f;
  if (c != i) {
    const float* A = cap + (size_t)c * 40960;
    const float* B = cap + (size_t)i * 40960;
    for (int e = threadIdx.x; e < 40960; e += 256) { float d = A[e] - B[e]; ss += d * d; }
  }
  float t = block_red_sum(ss);
  if (threadIdx.x == 0) dup[b] = (c != i && t <= 1e-6f) ? 1 : 0;
}

// Wcat row n: even n -> Wl[n/2], odd n -> Wg[n/2]
__global__ __launch_bounds__(256) void wconv_kernel(
    const float* __restrict__ Wl, const float* __restrict__ Wg, u16* __restrict__ out) {
  const size_t idx = ((size_t)blockIdx.x * 256 + threadIdx.x) * 4;
  const int n = (int)(idx >> 11);
  const int k = (int)(idx & 2047);
  const float* src = (n & 1) ? &Wg[(size_t)(n >> 1) * 2048 + k] : &Wl[(size_t)(n >> 1) * 2048 + k];
  float4 v = *(const float4*)src;
  ushort4 o;
  o.x = f2bf(v.x); o.y = f2bf(v.y); o.z = f2bf(v.z); o.w = f2bf(v.w);
  *(ushort4*)&out[idx] = o;
}

// fp32 rows -> bf16, grouped in 48-row padded blocks (pad rows zeroed).
__global__ __launch_bounds__(256) void bfpad_kernel(
    const float* __restrict__ src, u16* __restrict__ dst, int nrows) {
  const int b = blockIdx.x;
  const int blk = b / 48, r = b - blk * 48;
  u16* orow = dst + (size_t)b * 1024;
  const int tid = threadIdx.x;
  ushort4 o = {0, 0, 0, 0};
  if (r < nrows) {
    const float4 v = *(const float4*)&src[((size_t)blk * nrows + r) * 1024 + tid * 4];
    o.x = f2bf(v.x); o.y = f2bf(v.y); o.z = f2bf(v.z); o.w = f2bf(v.w);
  }
  *(ushort4*)&orow[tid * 4] = o;
}

// SS[b][s][s'] = src_b[s] . src_b[s'], fp32; zero outside nrows. grid (48, 32)
__global__ __launch_bounds__(256) void ss_kernel(
    const float* __restrict__ src, float* __restrict__ out, int nrows) {
  const int s = blockIdx.x, b = blockIdx.y;
  float* orow = out + ((size_t)b * 48 + s) * 64;
  __shared__ float Ls[1024];
  const int tid = threadIdx.x;
  if (s < nrows)
    *(float4*)&Ls[tid * 4] = *(const float4*)&src[((size_t)b * nrows + s) * 1024 + tid * 4];
  __syncthreads();
  const int s2 = tid >> 2, koff = (tid & 3) * 256;
  float acc = 0.f;
  if (s < nrows && s2 < nrows) {
    const float* r2 = src + ((size_t)b * nrows + s2) * 1024 + koff;
    for (int k = 0; k < 256; k += 4) {
      float4 a = *(const float4*)&Ls[koff + k];
      float4 bb = *(const float4*)&r2[k];
      acc += a.x * bb.x + a.y * bb.y + a.z * bb.z + a.w * bb.w;
    }
  }
  acc += __shfl_xor(acc, 1, 64);
  acc += __shfl_xor(acc, 2, 64);
  if ((tid & 3) == 0) orow[s2] = acc;
}

// ---------------------------------------------------------------- GEMMs
typedef short bf16x8 __attribute__((ext_vector_type(8)));
typedef float f32x4 __attribute__((ext_vector_type(4)));

// C[m][n] = sum_{k<1024} A[m*1024+k] * B[n*2048+koff+k], out bf16.
// trans=0: out[m*2048+n].  trans=1 (SWT): m=(blk*48+s) -> out[(blk*2048+n)*64+s].
__global__ __launch_bounds__(256) void gemm_flex_kernel(
    const u16* __restrict__ A, const u16* __restrict__ B, u16* __restrict__ Cout,
    int koff, int trans) {
  __shared__ u16 As[128 * 32];
  __shared__ u16 Bs[128 * 32];
  const int tid = threadIdx.x;
  const int lane = tid & 63;
  const int wave = tid >> 6;
  const int wm = (wave >> 1) * 64;
  const int wn = (wave & 1) * 64;
  const int bm = blockIdx.x * 128;
  const int bn = blockIdx.y * 128;
  const int lr = lane & 15;
  const int lq = lane >> 4;
  f32x4 acc[4][4] = {};
  const int e0 = tid * 8;
  const int r0 = e0 >> 5;
  const int c0 = e0 & 31;
  const u16* Ag0 = A + (size_t)(bm + r0) * 1024 + c0;
  const u16* Ag1 = A + (size_t)(bm + r0 + 64) * 1024 + c0;
  const u16* Bg0 = B + (size_t)(bn + r0) * 2048 + koff + c0;
  const u16* Bg1 = B + (size_t)(bn + r0 + 64) * 2048 + koff + c0;
  u16* As0 = As + e0; u16* As1 = As + e0 + 2048;
  u16* Bs0 = Bs + e0; u16* Bs1 = Bs + e0 + 2048;
  for (int k0 = 0; k0 < 1024; k0 += 32) {
    __builtin_amdgcn_global_load_lds((const __attribute__((address_space(1))) void*)(Ag0 + k0),
                                     (__attribute__((address_space(3))) void*)As0, 16, 0, 0);
    __builtin_amdgcn_global_load_lds((const __attribute__((address_space(1))) void*)(Ag1 + k0),
                                     (__attribute__((address_space(3))) void*)As1, 16, 0, 0);
    __builtin_amdgcn_global_load_lds((const __attribute__((address_space(1))) void*)(Bg0 + k0),
                                     (__attribute__((address_space(3))) void*)Bs0, 16, 0, 0);
    __builtin_amdgcn_global_load_lds((const __attribute__((address_space(1))) void*)(Bg1 + k0),
                                     (__attribute__((address_space(3))) void*)Bs1, 16, 0, 0);
    __syncthreads();
    bf16x8 af[4], bfr[4];
#pragma unroll
    for (int mi = 0; mi < 4; mi++)
      af[mi] = *(const bf16x8*)&As[(wm + mi * 16 + lr) * 32 + lq * 8];
#pragma unroll
    for (int ni = 0; ni < 4; ni++)
      bfr[ni] = *(const bf16x8*)&Bs[(wn + ni * 16 + lr) * 32 + lq * 8];
#pragma unroll
    for (int mi = 0; mi < 4; mi++)
#pragma unroll
      for (int ni = 0; ni < 4; ni++)
        acc[mi][ni] = __builtin_amdgcn_mfma_f32_16x16x32_bf16(af[mi], bfr[ni], acc[mi][ni], 0, 0, 0);
    __syncthreads();
  }
#pragma unroll
  for (int mi = 0; mi < 4; mi++) {
#pragma unroll
    for (int ni = 0; ni < 4; ni++) {
      const int col = bn + wn + ni * 16 + lr;
      const int rowb = bm + wm + mi * 16 + lq * 4;
      if (!trans) {
#pragma unroll
        for (int r = 0; r < 4; r++)
          Cout[(size_t)(rowb + r) * 2048 + col] = f2bf(acc[mi][ni][r]);
      } else {
#pragma unroll
        for (int r = 0; r < 4; r++) {
          const int m = rowb + r;
          const int blk = m / 48, s = m - blk * 48;
          Cout[((size_t)blk * 2048 + col) * 64 + s] = f2bf(acc[mi][ni][r]);
        }
      }
    }
  }
}

// E[m][n] = sum_k imgbf[m][k]*capbf[n][k], fp32 out, M=N=1536, K=1024. grid (12,12)
__global__ __launch_bounds__(256) void gemm_e_kernel(
    const u16* __restrict__ A, const u16* __restrict__ B, float* __restrict__ C) {
  __shared__ u16 As[128 * 32];
  __shared__ u16 Bs[128 * 32];
  const int tid = threadIdx.x;
  const int lane = tid & 63;
  const int wave = tid >> 6;
  const int wm = (wave >> 1) * 64;
  const int wn = (wave & 1) * 64;
  const int bm = blockIdx.x * 128;
  const int bn = blockIdx.y * 128;
  const int lr = lane & 15;
  const int lq = lane >> 4;
  f32x4 acc[4][4] = {};
  const int e0 = tid * 8;
  const int r0 = e0 >> 5;
  const int c0 = e0 & 31;
  const u16* Ag0 = A + (size_t)(bm + r0) * 1024 + c0;
  const u16* Ag1 = A + (size_t)(bm + r0 + 64) * 1024 + c0;
  const u16* Bg0 = B + (size_t)(bn + r0) * 1024 + c0;
  const u16* Bg1 = B + (size_t)(bn + r0 + 64) * 1024 + c0;
  u16* As0 = As + e0; u16* As1 = As + e0 + 2048;
  u16* Bs0 = Bs + e0; u16* Bs1 = Bs + e0 + 2048;
  for (int k0 = 0; k0 < 1024; k0 += 32) {
    __builtin_amdgcn_global_load_lds((const __attribute__((address_space(1))) void*)(Ag0 + k0),
                                     (__attribute__((address_space(3))) void*)As0, 16, 0, 0);
    __builtin_amdgcn_global_load_lds((const __attribute__((address_space(1))) void*)(Ag1 + k0),
                                     (__attribute__((address_space(3))) void*)As1, 16, 0, 0);
    __builtin_amdgcn_global_load_lds((const __attribute__((address_space(1))) void*)(Bg0 + k0),
                                     (__attribute__((address_space(3))) void*)Bs0, 16, 0, 0);
    __builtin_amdgcn_global_load_lds((const __attribute__((address_space(1))) void*)(Bg1 + k0),
                                     (__attribute__((address_space(3))) void*)Bs1, 16, 0, 0);
    __syncthreads();
    bf16x8 af[4], bfr[4];
#pragma unroll
    for (int mi = 0; mi < 4; mi++)
      af[mi] = *(const bf16x8*)&As[(wm + mi * 16 + lr) * 32 + lq * 8];
#pragma unroll
    for (int ni = 0; ni < 4; ni++)
      bfr[ni] = *(const bf16x8*)&Bs[(wn + ni * 16 + lr) * 32 + lq * 8];
#pragma unroll
    for (int mi = 0; mi < 4; mi++)
#pragma unroll
      for (int ni = 0; ni < 4; ni++)
        acc[mi][ni] = __builtin_amdgcn_mfma_f32_16x16x32_bf16(af[mi], bfr[ni], acc[mi][ni], 0, 0, 0);
    __syncthreads();
  }
#pragma unroll
  for (int mi = 0; mi < 4; mi++)
#pragma unroll
    for (int ni = 0; ni < 4; ni++) {
      const int col = bn + wn + ni * 16 + lr;
      const int rowb = bm + wm + mi * 16 + lq * 4;
#pragma unroll
      for (int r = 0; r < 4; r++)
        C[(size_t)(rowb + r) * 1536 + col] = acc[mi][ni][r];
    }
}

// ---------------------------------------------------------------- wcgate GEMM
// u-rows: M = P*NQ, m = pl*NQ+q, pairs sIdx-grouped (sIdx = (p0+pl)>>5).
// acc[m][n] = attnTg[m][0:64].SWT[sIdx][n][0:64]  (+ step1: q1[m][0:1024].Wcat[n][0:1024])
// epilogue: lin/gate (even/odd n) (+ step0: QW0[rIdx*48+q][n]) + bias -> gated u -> Uout bf16
// Grid (16, Mt), x = n-tile FASTEST: the concurrent block window spans few m-tiles x all
// 16 n-tiles, so the large A operand is fetched ~once; small B (Wcat+SWT, 16 MB) streams
// from L3. Dense sequential raster preserves the ~1.35 TB/s L2-fill rate (R3/R5 measured).
__global__ __launch_bounds__(256) void wcgate_kernel(
    const u16* __restrict__ attnTg, const u16* __restrict__ q2nd,
    const u16* __restrict__ qref, const u16* __restrict__ SWT,
    const u16* __restrict__ Wcat, const u16* __restrict__ qw0,
    const float* __restrict__ bl, const float* __restrict__ bg,
    u16* __restrict__ Uout, int p0, int NQ, int step) {
  __shared__ u16 sh[128 * 72];
  u16* As = sh;
  u16* Bs = sh + 4096;
  const int tid = threadIdx.x;
  const int lane = tid & 63;
  const int wave = tid >> 6;
  const int wm = (wave >> 1) * 64;
  const int wn = (wave & 1) * 64;
  const int bn = blockIdx.x * 128;   // n fastest
  const int bm = blockIdx.y * 128;
  const int lr = lane & 15;
  const int lq = lane >> 4;
  const int sIdx = (p0 + bm / NQ) >> 5;
  f32x4 acc[4][4] = {};
  const int e0 = tid * 8;
  const int r0 = e0 >> 5;
  const int c0 = e0 & 31;
  u16* As0 = As + e0; u16* As1 = As + e0 + 2048;
  u16* Bs0 = Bs + e0; u16* Bs1 = Bs + e0 + 2048;
  {  // region 1: K=64, A stride 64, B = SWT stride 64
    const u16* Ag0 = attnTg + (size_t)(bm + r0) * 64 + c0;
    const u16* Ag1 = attnTg + (size_t)(bm + r0 + 64) * 64 + c0;
    const u16* Bg0 = SWT + ((size_t)sIdx * 2048 + bn + r0) * 64 + c0;
    const u16* Bg1 = SWT + ((size_t)sIdx * 2048 + bn + r0 + 64) * 64 + c0;
    for (int k0 = 0; k0 < 64; k0 += 32) {
      __builtin_amdgcn_global_load_lds((const __attribute__((address_space(1))) void*)(Ag0 + k0),
                                       (__attribute__((address_space(3))) void*)As0, 16, 0, 0);
      __builtin_amdgcn_global_load_lds((const __attribute__((address_space(1))) void*)(Ag1 + k0),
                                       (__attribute__((address_space(3))) void*)As1, 16, 0, 0);
      __builtin_amdgcn_global_load_lds((const __attribute__((address_space(1))) void*)(Bg0 + k0),
                                       (__attribute__((address_space(3))) void*)Bs0, 16, 0, 0);
      __builtin_amdgcn_global_load_lds((const __attribute__((address_space(1))) void*)(Bg1 + k0),
                                       (__attribute__((address_space(3))) void*)Bs1, 16, 0, 0);
      __syncthreads();
      bf16x8 af[4], bfr[4];
#pragma unroll
      for (int mi = 0; mi < 4; mi++)
        af[mi] = *(const bf16x8*)&As[(wm + mi * 16 + lr) * 32 + lq * 8];
#pragma unroll
      for (int ni = 0; ni < 4; ni++)
        bfr[ni] = *(const bf16x8*)&Bs[(wn + ni * 16 + lr) * 32 + lq * 8];
#pragma unroll
      for (int mi = 0; mi < 4; mi++)
#pragma unroll
        for (int ni = 0; ni < 4; ni++)
          acc[mi][ni] = __builtin_amdgcn_mfma_f32_16x16x32_bf16(af[mi], bfr[ni], acc[mi][ni], 0, 0, 0);
      __syncthreads();
    }
  }
  if (step) {  // region 2: K=1024, A = q1 stride 1024, B = Wcat stride 2048
    const u16* Ag0 = q2nd + (size_t)(bm + r0) * 1024 + c0;
    const u16* Ag1 = q2nd + (size_t)(bm + r0 + 64) * 1024 + c0;
    const u16* Bg0 = Wcat + (size_t)(bn + r0) * 2048 + c0;
    const u16* Bg1 = Wcat + (size_t)(bn + r0 + 64) * 2048 + c0;
    for (int k0 = 0; k0 < 1024; k0 += 32) {
      __builtin_amdgcn_global_load_lds((const __attribute__((address_space(1))) void*)(Ag0 + k0),
                                       (__attribute__((address_space(3))) void*)As0, 16, 0, 0);
      __builtin_amdgcn_global_load_lds((const __attribute__((address_space(1))) void*)(Ag1 + k0),
                                       (__attribute__((address_space(3))) void*)As1, 16, 0, 0);
      __builtin_amdgcn_global_load_lds((const __attribute__((address_space(1))) void*)(Bg0 + k0),
                                       (__attribute__((address_space(3))) void*)Bs0, 16, 0, 0);
      __builtin_amdgcn_global_load_lds((const __attribute__((address_space(1))) void*)(Bg1 + k0),
                                       (__attribute__((address_space(3))) void*)Bs1, 16, 0, 0);
      __syncthreads();
      bf16x8 af[4], bfr[4];
#pragma unroll
      for (int mi = 0; mi < 4; mi++)
        af[mi] = *(const bf16x8*)&As[(wm + mi * 16 + lr) * 32 + lq * 8];
#pragma unroll
      for (int ni = 0; ni < 4; ni++)
        bfr[ni] = *(const bf16x8*)&Bs[(wn + ni * 16 + lr) * 32 + lq * 8];
#pragma unroll
      for (int mi = 0; mi < 4; mi++)
#pragma unroll
        for (int ni = 0; ni < 4; ni++)
          acc[mi][ni] = __builtin_amdgcn_mfma_f32_16x16x32_bf16(af[mi], bfr[ni], acc[mi][ni], 0, 0, 0);
      __syncthreads();
    }
  }
  // epilogue: C/D layout col=lane&15, row=quad*4+reg
  const bool evn = (lane & 1) == 0;
#pragma unroll
  for (int mi = 0; mi < 4; mi++) {
#pragma unroll
    for (int ni = 0; ni < 4; ni++) {
      const int ncol = bn + wn + ni * 16 + lr;
      const int d = ncol >> 1;
      const int dloc = (wn + ni * 16 + lr) >> 1;
      const int rowloc0 = wm + mi * 16 + lq * 4;
      const float blv = bl[d];
      const float bgv = bg[d];
#pragma unroll
      for (int r = 0; r < 4; r++) {
        const float v = acc[mi][ni][r];
        const float o = __shfl_xor(v, 1, 64);
        float lin = (evn ? v : o) + blv;
        float gt = (evn ? o : v) + bgv;
        const int m = bm + rowloc0 + r;
        const int pl = m / NQ;
        const int q = m - pl * NQ;
        float qv;
        if (step == 0) {
          const int rIdx = (p0 + pl) & 31;
          const u32 qwpair = *(const u32*)&qw0[(size_t)(rIdx * 48 + q) * 2048 + (ncol & ~1)];
          lin += bf2f((u16)(qwpair & 0xffffu));
          gt += bf2f((u16)(qwpair >> 16));
          qv = bf2f(qref[(size_t)(rIdx * 48 + q) * 1024 + d]);
        } else {
          qv = bf2f(qref[(size_t)m * 1024 + d]);
        }
        lin = fminf(fmaxf(lin, -30.f), 30.f);
        gt = fminf(fmaxf(gt, -30.f), 30.f);
        const float g = 1.f / (1.f + __expf(-gt));
        const float e2 = __expf(-2.f * lin);
        const float th = (1.f - e2) / (1.f + e2);
        const float u = qv * g + th * (1.f - g);
        if (evn) sh[(rowloc0 + r) * 72 + dloc] = f2bf(u);
      }
    }
  }
  __syncthreads();
  {  // coalesced store of 128x64 u16 tile
    const int rowloc = tid >> 1, half = tid & 1;
    u16* dst = Uout + (size_t)(bm + rowloc) * 1024 + (bn >> 1) + half * 32;
    const u16* srcl = sh + rowloc * 72 + half * 32;
#pragma unroll
    for (int v2 = 0; v2 < 4; v2++)
      *(bf16x8*)(dst + v2 * 8) = *(const bf16x8*)(srcl + v2 * 8);
  }
}

// q_new = u / (||u|| + eps), in-place (M x 1024 bf16). One wave per row.
__global__ __launch_bounds__(256) void qnorm_kernel(u16* __restrict__ Q) {
  const int m = blockIdx.x * 4 + (threadIdx.x >> 6);
  const int lane = threadIdx.x & 63;
  u16* p = Q + (size_t)m * 1024;
  float v[16];
  float ss = 0.f;
#pragma unroll
  for (int t = 0; t < 4; t++) {
    ushort4 uv = *(const ushort4*)&p[t * 256 + lane * 4];
    float a = bf2f(uv.x), b = bf2f(uv.y), c = bf2f(uv.z), dd = bf2f(uv.w);
    v[t * 4 + 0] = a; v[t * 4 + 1] = b; v[t * 4 + 2] = c; v[t * 4 + 3] = dd;
    ss += a * a + b * b + c * c + dd * dd;
  }
  ss = wave_red_sum(ss);
  const float inv = 1.f / (sqrtf(ss) + EPSF);
#pragma unroll
  for (int t = 0; t < 4; t++) {
    ushort4 ov;
    ov.x = f2bf(v[t * 4 + 0] * inv); ov.y = f2bf(v[t * 4 + 1] * inv);
    ov.z = f2bf(v[t * 4 + 2] * inv); ov.w = f2bf(v[t * 4 + 3] * inv);
    *(ushort4*)&p[t * 256 + lane * 4] = ov;
  }
}

// ---------------------------------------------------------------- fused attention step
// A (steps 1,2): QK^T MFMA; step0: logits = E block. B: leaky/l2norm/softmax (fp32).
// C': num = a.E-col, pss = a^T SS a (LDS algebra). Writes attnT (steps 0,1).
template <int NS, int NQ>
__global__ __launch_bounds__(256) void attn_step_kernel(
    const u16* __restrict__ Sbf, const float* __restrict__ E,
    const float* __restrict__ SS, const float* __restrict__ refn,
    const u16* __restrict__ qsrc, u16* __restrict__ attnTg,
    const int* __restrict__ dup, float* __restrict__ total,
    int p0, int t2i, int step) {
  constexpr int NQW = NQ / 4;
  const int pl = blockIdx.x;
  const int plg = p0 + pl;                 // pairs sIdx-grouped
  const int sIdx = plg >> 5, rIdx = plg & 31;
  const int c = t2i ? rIdx : sIdx;
  const int i = t2i ? sIdx : rIdx;
  const int gp = c * 32 + i;
  const u16* Sb = Sbf + (size_t)sIdx * 48 * 1024;
  const float* rn = refn + (size_t)rIdx * NQ;
  const u16* Qb = qsrc + (size_t)pl * NQ * 1024;

  __shared__ float redbuf[9600];   // phase A red[4][2400]; later Elw[48*65] + SSl[48*65]
  __shared__ float attnS[2304];
  __shared__ float redcos[48];
  float* Elw = redbuf;
  float* SSl = redbuf + 3120;

  const int tid = threadIdx.x;
  const int lane = tid & 63, wave = tid >> 6;
  const int lr = lane & 15, quad = lane >> 4;

  if (step == 0) {
    for (int e = tid; e < 2304; e += 256) {
      int s, q; float v;
      if (t2i) { s = e / 48; q = e - s * 48; v = E[(size_t)(i * 48 + s) * 1536 + c * 48 + q]; }
      else     { q = e / 48; s = e - q * 48; v = E[(size_t)(i * 48 + q) * 1536 + c * 48 + s]; }
      attnS[s * 48 + q] = v;
    }
  } else {
    // phase A: wave w covers k in [w*256, w*256+256); 8 slabs x 3x3 MFMA frags
    f32x4 acc[3][3] = {};
    const int kw = wave * 256;
    const u16* Arow[3]; const u16* Brow[3];
#pragma unroll
    for (int a = 0; a < 3; a++) {
      Arow[a] = Sb + (size_t)(a * 16 + lr) * 1024 + quad * 8;
      Brow[a] = Qb + (size_t)(a * 16 + lr) * 1024 + quad * 8;
    }
    bf16x8 A0[3], B0[3], A1[3], B1[3];
#pragma unroll
    for (int a = 0; a < 3; a++) {
      A0[a] = *(const bf16x8*)(Arow[a] + kw);
      B0[a] = *(const bf16x8*)(Brow[a] + kw);
    }
#pragma unroll
    for (int j = 0; j < 8; j++) {
      if (j < 7) {
        const int kn = kw + (j + 1) * 32;
#pragma unroll
        for (int a = 0; a < 3; a++) {
          A1[a] = *(const bf16x8*)(Arow[a] + kn);
          B1[a] = *(const bf16x8*)(Brow[a] + kn);
        }
      }
#pragma unroll
      for (int a = 0; a < 3; a++)
#pragma unroll
        for (int b = 0; b < 3; b++)
          acc[a][b] = __builtin_amdgcn_mfma_f32_16x16x32_bf16(A0[a], B0[b], acc[a][b], 0, 0, 0);
#pragma unroll
      for (int a = 0; a < 3; a++) { A0[a] = A1[a]; B0[a] = B1[a]; }
    }
    float* myred = redbuf + wave * 2400;
#pragma unroll
    for (int a = 0; a < 3; a++)
#pragma unroll
      for (int b = 0; b < 3; b++) {
        const int col = b * 16 + lr;
        const int row0 = a * 16 + quad * 4;
#pragma unroll
        for (int r = 0; r < 4; r++)
          myred[(row0 + r) * 50 + col] = acc[a][b][r];
      }
    __syncthreads();
#pragma unroll
    for (int t = 0; t < 9; t++) {
      const int e = tid + t * 256;
      const int s = e / 48, q = e - s * 48;
      const int o = s * 50 + q;
      attnS[e] = redbuf[o] + redbuf[2400 + o] + redbuf[4800 + o] + redbuf[7200 + o];
    }
  }
  __syncthreads();
  // load Elw / SSl (into dead red space) + leaky/l2norm in one interval
  for (int e = tid; e < 2304; e += 256) {
    int s, q; float v;
    if (t2i) { s = e / 48; q = e - s * 48; v = E[(size_t)(i * 48 + s) * 1536 + c * 48 + q]; }
    else     { q = e / 48; s = e - q * 48; v = E[(size_t)(i * 48 + q) * 1536 + c * 48 + s]; }
    Elw[s * 65 + q] = v;
  }
  for (int e = tid; e < 48 * 64; e += 256) {
    const int s = e >> 6, s2 = e & 63;
    SSl[s * 65 + s2] = SS[((size_t)sIdx * 48 + s) * 64 + s2];
  }
  if (tid < NS) {
    float row[NQ];
    float ss = 0.f;
#pragma unroll
    for (int q = 0; q < NQ; q++) {
      float v = attnS[tid * 48 + q];
      v = (v > 0.f) ? v : SLOPEF * v;
      row[q] = v; ss += v * v;
    }
    const float inv = 1.f / (sqrtf(ss) + EPSF);
#pragma unroll
    for (int q = 0; q < NQ; q++) attnS[tid * 48 + q] = row[q] * inv;
  }
  __syncthreads();
  if (tid < NQ) {
    float mx = -1e30f;
#pragma unroll
    for (int s = 0; s < NS; s++) mx = fmaxf(mx, attnS[s * 48 + tid]);
    float ex[NS]; float sum = 0.f;
#pragma unroll
    for (int s = 0; s < NS; s++) {
      float t = __expf(SMOOTHF * (attnS[s * 48 + tid] - mx));
      ex[s] = t; sum += t;
    }
    const float inv = 1.f / sum;
#pragma unroll
    for (int s = 0; s < NS; s++) attnS[s * 48 + tid] = ex[s] * inv;
  }
  __syncthreads();
  // write attnT rows (steps 0,1): [m = pl*NQ+q][64 s]
  if (step < 2) {
    for (int e = tid; e < NQ * 64; e += 256) {
      const int q = e >> 6, s = e & 63;
      attnTg[((size_t)(pl * NQ + q)) * 64 + s] = (s < 48) ? f2bf(attnS[s * 48 + q]) : (u16)0;
    }
  }
  // phase C': per-q num & pss via E/SS algebra
  {
    const int qbase = wave * NQW;
#pragma unroll
    for (int qq = 0; qq < NQW; qq++) {
      const int q = qbase + qq;
      const float a_l = (lane < 48) ? attnS[lane * 48 + q] : 0.f;
      float t = 0.f;
#pragma unroll
      for (int s = 0; s < NS; s++)
        t += attnS[s * 48 + q] * SSl[s * 65 + lane];
      float pssv = wave_red_sum(a_l * t);
      float numv = wave_red_sum(a_l * Elw[lane * 65 + q]);
      if (lane == 0) redcos[q] = numv / fmaxf(rn[q] * sqrtf(pssv), EPSF);
    }
  }
  __syncthreads();
  if (tid == 0) {
    float sim = 0.f;
#pragma unroll
    for (int q = 0; q < NQ; q++) sim += redcos[q];
    sim *= (1.0f / NQ);
    atomicAdd(&total[gp], dup[gp] ? -1.0f : sim);
  }
}

// ---------------------------------------------------------------- launcher
extern "C" void kernel_launch(void* const* d_in, const int* in_sizes, int n_in,
                              void* d_out, int out_size, void* d_ws, size_t ws_size,
                              hipStream_t stream) {
  (void)in_sizes; (void)n_in;
  const float* img = (const float*)d_in[0];
  const float* cap = (const float*)d_in[1];
  const float* W_lt2i = (const float*)d_in[2];
  const float* b_lt2i = (const float*)d_in[3];
  const float* W_gt2i = (const float*)d_in[4];
  const float* b_gt2i = (const float*)d_in[5];
  const float* W_li2t = (const float*)d_in[6];
  const float* b_li2t = (const float*)d_in[7];
  const float* W_gi2t = (const float*)d_in[8];
  const float* b_gi2t = (const float*)d_in[9];
  float* total = (float*)d_out;

  char* ws = (char*)d_ws;
  size_t off = 0;
  auto alloc = [&](size_t b) { void* p = ws + off; off += (b + 255) & ~(size_t)255; return p; };
  u16* Wcat = (u16*)alloc((size_t)2048 * 2048 * 2);
  u16* imgbf = (u16*)alloc((size_t)32 * 48 * 1024 * 2);
  u16* capbf = (u16*)alloc((size_t)32 * 48 * 1024 * 2);
  float* capn = (float*)alloc(1280 * 4);
  float* imgn = (float*)alloc(1152 * 4);
  int* dupb = (int*)alloc(1024 * 4);
  u16* SWT = (u16*)alloc((size_t)32 * 2048 * 64 * 2);
  float* E = (float*)alloc((size_t)1536 * 1536 * 4);
  float* SSi = (float*)alloc((size_t)32 * 48 * 64 * 4);
  float* SSc = (float*)alloc((size_t)32 * 48 * 64 * 4);
  u16* QW0 = (u16*)alloc((size_t)1536 * 2048 * 2);
  const size_t fixed = off;

  static const int cands[6] = {1024, 512, 256, 128, 64, 32};
  int P = 32;
  for (int ci = 0; ci < 6; ci++) {
    const int cand = cands[ci];
    const size_t cA = (((size_t)cand * 40 * 1024 * 2) + 255) & ~(size_t)255;
    const size_t aT = (((size_t)cand * 40 * 64 * 2) + 255) & ~(size_t)255;
    if (fixed + 2 * cA + aT <= ws_size) { P = cand; break; }
  }
  u16* catA = (u16*)alloc((size_t)P * 40 * 1024 * 2);
  u16* catB = (u16*)alloc((size_t)P * 40 * 1024 * 2);
  u16* attnTg = (u16*)alloc((size_t)P * 40 * 64 * 2);

  hipMemsetAsync(d_out, 0, (size_t)out_size * sizeof(float), stream);
  hipMemsetAsync(SWT, 0, (size_t)32 * 2048 * 64 * 2, stream);
  rownorm_kernel<<<dim3(2432), dim3(256), 0, stream>>>(cap, img, capn, imgn);
  dup_kernel<<<dim3(1024), dim3(256), 0, stream>>>(cap, dupb);
  bfpad_kernel<<<dim3(1536), dim3(256), 0, stream>>>(cap, capbf, 40);
  bfpad_kernel<<<dim3(1536), dim3(256), 0, stream>>>(img, imgbf, 36);
  gemm_e_kernel<<<dim3(12, 12), dim3(256), 0, stream>>>(imgbf, capbf, E);
  ss_kernel<<<dim3(48, 32), dim3(256), 0, stream>>>(img, SSi, 36);
  ss_kernel<<<dim3(48, 32), dim3(256), 0, stream>>>(cap, SSc, 40);

  const int nch = 1024 / P;
  for (int dir = 0; dir < 2; dir++) {
    const int t2i = (dir == 0) ? 1 : 0;
    const float* Wl = t2i ? W_lt2i : W_li2t;
    const float* Wg = t2i ? W_gt2i : W_gi2t;
    const float* bl = t2i ? b_lt2i : b_li2t;
    const float* bg = t2i ? b_gt2i : b_gi2t;
    const u16* Sbf = t2i ? imgbf : capbf;
    const u16* Refbf = t2i ? capbf : imgbf;
    const float* SSd = t2i ? SSi : SSc;
    const float* refn = t2i ? capn : imgn;
    const int NQ = t2i ? 40 : 36;
    const int Mrows = P * NQ;
    const int Mt = Mrows / 128;
    wconv_kernel<<<dim3(4096), dim3(256), 0, stream>>>(Wl, Wg, Wcat);
    gemm_flex_kernel<<<dim3(12, 16), dim3(256), 0, stream>>>(Sbf, Wcat, SWT, 1024, 1);
    gemm_flex_kernel<<<dim3(12, 16), dim3(256), 0, stream>>>(Refbf, Wcat, QW0, 0, 0);
    for (int ch = 0; ch < nch; ch++) {
      const int p0 = ch * P;
      for (int step = 0; step < 3; step++) {
        const u16* qsrc = (step == 1) ? catB : catA;
        if (t2i)
          attn_step_kernel<36, 40><<<dim3(P), dim3(256), 0, stream>>>(
              Sbf, E, SSd, refn, qsrc, attnTg, dupb, total, p0, 1, step);
        else
          attn_step_kernel<40, 36><<<dim3(P), dim3(256), 0, stream>>>(
              Sbf, E, SSd, refn, qsrc, attnTg, dupb, total, p0, 0, step);
        if (step == 0) {
          wcgate_kernel<<<dim3(16, Mt), dim3(256), 0, stream>>>(
              attnTg, catA, Refbf, SWT, Wcat, QW0, bl, bg, catB, p0, NQ, 0);
          qnorm_kernel<<<dim3(Mrows / 4), dim3(256), 0, stream>>>(catB);
        } else if (step == 1) {
          wcgate_kernel<<<dim3(16, Mt), dim3(256), 0, stream>>>(
              attnTg, catB, catB, SWT, Wcat, QW0, bl, bg, catA, p0, NQ, 1);
          qnorm_kernel<<<dim3(Mrows / 4), dim3(256), 0, stream>>>(catA);
        }
      }
    }
  }
}